// Round 5
// baseline (287.803 us; speedup 1.0000x reference)
//
#include <hip/hip_runtime.h>

// EdgeMLP: f = (relu(x@W1+b1)@W2+b2) for both edge sets, then masked pairwise
// cosine similarity out[i][j] = (cls1[i]==cls2[j]) * dot(f1_hat[i], f2_hat[j]).
// Stage 1: normalized features (bf16) + int labels into ws.
// Stage 2 v3: DIRECT-STORE pair kernel. A/B evidence from R0/R3/R4 shows store
// contiguity is irrelevant on MI355X (64B-segment strided == 2KB contiguous
// within 2%), so the LDS staging round-trip is pure overhead. Swapped-operand
// mfma_f32_16x16x32_bf16 leaves each lane with a float4 of 4 consecutive
// output columns of one row -> mask + one global_store_dwordx4 per tile,
// straight from the MFMA destination registers. No LDS, no barriers, no
// waitcnt drains; occupancy is VGPR-bound only.

typedef __bf16 bf16x8 __attribute__((ext_vector_type(8)));
typedef float floatx4 __attribute__((ext_vector_type(4)));

__global__ __launch_bounds__(64) void mlp_norm_kernel(
    const float* __restrict__ e1, const float* __restrict__ e2,
    const float* __restrict__ W1, const float* __restrict__ b1,
    const float* __restrict__ W2, const float* __restrict__ b2,
    __bf16* __restrict__ f1b, __bf16* __restrict__ f2b,
    int* __restrict__ cls1, int* __restrict__ cls2, int N1, int N2)
{
    __shared__ __align__(16) float sW1[192];
    __shared__ float sb1[64];
    __shared__ __align__(16) float sW2[2048];
    __shared__ float sb2[32];
    for (int i = threadIdx.x; i < 192; i += 64) sW1[i] = W1[i];
    sb1[threadIdx.x] = b1[threadIdx.x];
    for (int i = threadIdx.x; i < 2048; i += 64) sW2[i] = W2[i];
    if (threadIdx.x < 32) sb2[threadIdx.x] = b2[threadIdx.x];
    __syncthreads();

    int t = blockIdx.x * 64 + threadIdx.x;
    if (t >= N1 + N2) return;

    const float* src;
    __bf16* fout;
    int* cout;
    int row;
    if (t < N1) { row = t;      src = e1 + (size_t)row * 4; fout = f1b; cout = cls1; }
    else        { row = t - N1; src = e2 + (size_t)row * 4; fout = f2b; cout = cls2; }

    float x0 = src[0], x1 = src[1], x2 = src[2];
    int lbl = (int)src[3];

    float f[32];
#pragma unroll
    for (int k = 0; k < 32; ++k) f[k] = sb2[k];

#pragma unroll 4
    for (int j = 0; j < 64; ++j) {
        float h = fmaf(x0, sW1[j], fmaf(x1, sW1[64 + j], fmaf(x2, sW1[128 + j], sb1[j])));
        h = fmaxf(h, 0.0f);
        const floatx4* w2 = (const floatx4*)(sW2 + j * 32);
#pragma unroll
        for (int k4 = 0; k4 < 8; ++k4) {
            floatx4 w = w2[k4];
            f[k4 * 4 + 0] = fmaf(h, w[0], f[k4 * 4 + 0]);
            f[k4 * 4 + 1] = fmaf(h, w[1], f[k4 * 4 + 1]);
            f[k4 * 4 + 2] = fmaf(h, w[2], f[k4 * 4 + 2]);
            f[k4 * 4 + 3] = fmaf(h, w[3], f[k4 * 4 + 3]);
        }
    }

    float ss = 0.0f;
#pragma unroll
    for (int k = 0; k < 32; ++k) ss = fmaf(f[k], f[k], ss);
    float n = sqrtf(ss);
    float scale = (n > 1e-20f) ? (1.0f / n) : 0.0f;

    // vectorized bf16 stores: 4 x 16B instead of 32 x 2B
    __bf16* dst = fout + (size_t)row * 32;
#pragma unroll
    for (int k8 = 0; k8 < 4; ++k8) {
        bf16x8 o;
#pragma unroll
        for (int k = 0; k < 8; ++k) o[k] = (__bf16)(f[k8 * 8 + k] * scale);
        *(bf16x8*)(dst + k8 * 8) = o;
    }
    cout[row] = lbl;
}

// Block = 4 independent waves; wave w owns output rows i0..i0+15, cols
// j0w..j0w+127 (8 tiles of 16x16). Swapped MFMA (verified R3/R4):
// D[m][n] = dot(f2[j+m], f1[i0+n]), n = lane&15 -> output row offset,
// m = (lane>>4)*4 + reg -> output col offset. Lane stores its float4 of
// consecutive cols directly: out[(i0+r16)*N2 + j0w + t*16 + q*4] = d masked.
__global__ __launch_bounds__(256) void pair_cos_kernel(
    const __bf16* __restrict__ f1b, const __bf16* __restrict__ f2b,
    const int* __restrict__ cls1, const int* __restrict__ cls2,
    float* __restrict__ out, int N2, int ncg)
{
    const int lane = threadIdx.x & 63;
    const int w = threadIdx.x >> 6;           // wave 0..3
    const int istrip = blockIdx.x / ncg;
    const int cg = blockIdx.x - istrip * ncg;
    const int i0 = istrip * 16;
    const int j0w = cg * 512 + w * 128;       // this wave's 128-col span
    const int r16 = lane & 15;
    const int q = lane >> 4;

    bf16x8 bfrag = *(const bf16x8*)(f1b + (size_t)(i0 + r16) * 32 + q * 8);
    const int c1 = cls1[i0 + r16];

    float* orow = out + (size_t)(i0 + r16) * N2 + j0w + q * 4;

#pragma unroll
    for (int t = 0; t < 8; ++t) {
        const int j = j0w + t * 16;
        bf16x8 afrag = *(const bf16x8*)(f2b + (size_t)(j + r16) * 32 + q * 8);
        int4 c2 = *(const int4*)(cls2 + j + q * 4);

        floatx4 acc = {0.0f, 0.0f, 0.0f, 0.0f};
        floatx4 d = __builtin_amdgcn_mfma_f32_16x16x32_bf16(afrag, bfrag, acc, 0, 0, 0);

        floatx4 m;
        m[0] = (c2.x == c1) ? d[0] : 0.0f;
        m[1] = (c2.y == c1) ? d[1] : 0.0f;
        m[2] = (c2.z == c1) ? d[2] : 0.0f;
        m[3] = (c2.w == c1) ? d[3] : 0.0f;
        *(floatx4*)(orow + t * 16) = m;
    }
}

extern "C" void kernel_launch(void* const* d_in, const int* in_sizes, int n_in,
                              void* d_out, int out_size, void* d_ws, size_t ws_size,
                              hipStream_t stream) {
    const float* e1 = (const float*)d_in[0];
    const float* e2 = (const float*)d_in[1];
    const float* W1 = (const float*)d_in[2];
    const float* b1 = (const float*)d_in[3];
    const float* W2 = (const float*)d_in[4];
    const float* b2 = (const float*)d_in[5];
    float* out = (float*)d_out;

    const int N1 = in_sizes[0] / 4;  // 8192
    const int N2 = in_sizes[1] / 4;  // 8192

    char* ws = (char*)d_ws;
    __bf16* f1b = (__bf16*)ws;                                   // N1*32 bf16
    __bf16* f2b = (__bf16*)(ws + (size_t)N1 * 64);               // N2*32 bf16
    int* cls1 = (int*)(ws + (size_t)(N1 + N2) * 64);             // N1 ints
    int* cls2 = cls1 + N1;                                       // N2 ints

    int nrows = N1 + N2;
    mlp_norm_kernel<<<(nrows + 63) / 64, 64, 0, stream>>>(
        e1, e2, W1, b1, W2, b2, f1b, f2b, cls1, cls2, N1, N2);

    int ncg = N2 / 512;                       // 16 col-groups of 512
    int nblocks = (N1 / 16) * ncg;            // 8192 blocks, 4 indep waves each
    pair_cos_kernel<<<nblocks, 256, 0, stream>>>(
        f1b, f2b, cls1, cls2, out, N2, ncg);
}

// Round 6
// 285.433 us; speedup vs baseline: 1.0083x; 1.0083x over previous
//
#include <hip/hip_runtime.h>

// EdgeMLP: f = (relu(x@W1+b1)@W2+b2) for both edge sets, then masked pairwise
// cosine similarity out[i][j] = (cls1[i]==cls2[j]) * dot(f1_hat[i], f2_hat[j]).
// Stage 1: normalized features (bf16) + int labels into ws.
// Stage 2 v4 (best-of consolidation): R0's wave decomposition (8192 waves,
// 32 tiles each — best measured residual) + R5's swapped-operand store form
// (one global_store_dwordx4 per tile, 4x fewer store instrs than R0's scalar
// strided stores). A/B evidence R0/R3/R4/R5: store contiguity irrelevant
// (64B==512B==2KB runs); LDS staging neutral; small waves regress (+10us).

typedef __bf16 bf16x8 __attribute__((ext_vector_type(8)));
typedef float floatx4 __attribute__((ext_vector_type(4)));

__global__ __launch_bounds__(64) void mlp_norm_kernel(
    const float* __restrict__ e1, const float* __restrict__ e2,
    const float* __restrict__ W1, const float* __restrict__ b1,
    const float* __restrict__ W2, const float* __restrict__ b2,
    __bf16* __restrict__ f1b, __bf16* __restrict__ f2b,
    int* __restrict__ cls1, int* __restrict__ cls2, int N1, int N2)
{
    __shared__ __align__(16) float sW1[192];
    __shared__ float sb1[64];
    __shared__ __align__(16) float sW2[2048];
    __shared__ float sb2[32];
    for (int i = threadIdx.x; i < 192; i += 64) sW1[i] = W1[i];
    sb1[threadIdx.x] = b1[threadIdx.x];
    for (int i = threadIdx.x; i < 2048; i += 64) sW2[i] = W2[i];
    if (threadIdx.x < 32) sb2[threadIdx.x] = b2[threadIdx.x];
    __syncthreads();

    int t = blockIdx.x * 64 + threadIdx.x;
    if (t >= N1 + N2) return;

    const float* src;
    __bf16* fout;
    int* cout;
    int row;
    if (t < N1) { row = t;      src = e1 + (size_t)row * 4; fout = f1b; cout = cls1; }
    else        { row = t - N1; src = e2 + (size_t)row * 4; fout = f2b; cout = cls2; }

    float x0 = src[0], x1 = src[1], x2 = src[2];
    int lbl = (int)src[3];

    float f[32];
#pragma unroll
    for (int k = 0; k < 32; ++k) f[k] = sb2[k];

#pragma unroll 4
    for (int j = 0; j < 64; ++j) {
        float h = fmaf(x0, sW1[j], fmaf(x1, sW1[64 + j], fmaf(x2, sW1[128 + j], sb1[j])));
        h = fmaxf(h, 0.0f);
        const floatx4* w2 = (const floatx4*)(sW2 + j * 32);
#pragma unroll
        for (int k4 = 0; k4 < 8; ++k4) {
            floatx4 w = w2[k4];
            f[k4 * 4 + 0] = fmaf(h, w[0], f[k4 * 4 + 0]);
            f[k4 * 4 + 1] = fmaf(h, w[1], f[k4 * 4 + 1]);
            f[k4 * 4 + 2] = fmaf(h, w[2], f[k4 * 4 + 2]);
            f[k4 * 4 + 3] = fmaf(h, w[3], f[k4 * 4 + 3]);
        }
    }

    float ss = 0.0f;
#pragma unroll
    for (int k = 0; k < 32; ++k) ss = fmaf(f[k], f[k], ss);
    float n = sqrtf(ss);
    float scale = (n > 1e-20f) ? (1.0f / n) : 0.0f;

    // vectorized bf16 stores: 4 x 16B instead of 32 x 2B
    __bf16* dst = fout + (size_t)row * 32;
#pragma unroll
    for (int k8 = 0; k8 < 4; ++k8) {
        bf16x8 o;
#pragma unroll
        for (int k = 0; k < 8; ++k) o[k] = (__bf16)(f[k8 * 8 + k] * scale);
        *(bf16x8*)(dst + k8 * 8) = o;
    }
    cout[row] = lbl;
}

// Each wave owns one 16-row x 512-col output region (32 tiles of 16x16).
// Swapped MFMA (verified R3/R4/R5): D[m][n] = dot(f2[j+m], f1[i0+n]) with
// n = lane&15 -> output row offset, m = (lane>>4)*4 + reg -> output col
// offset. Lane (r16,q) holds a float4 of consecutive cols q*4..q*4+3 of
// row i0+r16 -> mask against cls2[j+q*4..+3] == cls1[i0+r16], one
// global_store_dwordx4 per tile straight from the MFMA result.
__global__ __launch_bounds__(256) void pair_cos_kernel(
    const __bf16* __restrict__ f1b, const __bf16* __restrict__ f2b,
    const int* __restrict__ cls1, const int* __restrict__ cls2,
    float* __restrict__ out, int N2, int ncg)
{
    const int lane = threadIdx.x & 63;
    const int wid = blockIdx.x * 4 + (threadIdx.x >> 6);
    const int istrip = wid / ncg;
    const int cg = wid - istrip * ncg;
    const int i0 = istrip * 16;
    const int j0 = cg * 512;
    const int r16 = lane & 15;
    const int q = lane >> 4;

    bf16x8 bfrag = *(const bf16x8*)(f1b + (size_t)(i0 + r16) * 32 + q * 8);
    const int c1 = cls1[i0 + r16];

    float* orow = out + (size_t)(i0 + r16) * N2 + j0 + q * 4;

#pragma unroll 4
    for (int t = 0; t < 32; ++t) {
        const int j = j0 + t * 16;
        bf16x8 afrag = *(const bf16x8*)(f2b + (size_t)(j + r16) * 32 + q * 8);
        int4 c2 = *(const int4*)(cls2 + j + q * 4);

        floatx4 acc = {0.0f, 0.0f, 0.0f, 0.0f};
        floatx4 d = __builtin_amdgcn_mfma_f32_16x16x32_bf16(afrag, bfrag, acc, 0, 0, 0);

        floatx4 m;
        m[0] = (c2.x == c1) ? d[0] : 0.0f;
        m[1] = (c2.y == c1) ? d[1] : 0.0f;
        m[2] = (c2.z == c1) ? d[2] : 0.0f;
        m[3] = (c2.w == c1) ? d[3] : 0.0f;
        *(floatx4*)(orow + t * 16) = m;
    }
}

extern "C" void kernel_launch(void* const* d_in, const int* in_sizes, int n_in,
                              void* d_out, int out_size, void* d_ws, size_t ws_size,
                              hipStream_t stream) {
    const float* e1 = (const float*)d_in[0];
    const float* e2 = (const float*)d_in[1];
    const float* W1 = (const float*)d_in[2];
    const float* b1 = (const float*)d_in[3];
    const float* W2 = (const float*)d_in[4];
    const float* b2 = (const float*)d_in[5];
    float* out = (float*)d_out;

    const int N1 = in_sizes[0] / 4;  // 8192
    const int N2 = in_sizes[1] / 4;  // 8192

    char* ws = (char*)d_ws;
    __bf16* f1b = (__bf16*)ws;                                   // N1*32 bf16
    __bf16* f2b = (__bf16*)(ws + (size_t)N1 * 64);               // N2*32 bf16
    int* cls1 = (int*)(ws + (size_t)(N1 + N2) * 64);             // N1 ints
    int* cls2 = cls1 + N1;                                       // N2 ints

    int nrows = N1 + N2;
    mlp_norm_kernel<<<(nrows + 63) / 64, 64, 0, stream>>>(
        e1, e2, W1, b1, W2, b2, f1b, f2b, cls1, cls2, N1, N2);

    int ncg = N2 / 512;                 // 16 col-groups of 512
    int nwaves = (N1 / 16) * ncg;       // 8192 waves
    pair_cos_kernel<<<nwaves / 4, 256, 0, stream>>>(
        f1b, f2b, cls1, cls2, out, N2, ncg);
}